// Round 2
// baseline (729.275 us; speedup 1.0000x reference)
//
#include <hip/hip_runtime.h>
#include <math.h>

#define MAXN 0.996f /* (1-PROJ_EPS)/sqrt(c) */

__device__ __forceinline__ float wredsum(float v) {
#pragma unroll
  for (int o = 32; o > 0; o >>= 1) v += __shfl_xor(v, o);
  return v;
}

__device__ __forceinline__ float artanh_f(float x) {
  x = fminf(fmaxf(x, -1.0f + 1e-7f), 1.0f - 1e-7f);
  return 0.5f * (log1pf(x) - log1pf(-x));
}

// HypAgg+HypAct+logmap0 nonlinear chain applied to one aggregated row value
__device__ __forceinline__ float chainB(float acc) {
  float n0 = sqrtf(wredsum(acc * acc));
  float u0 = fmaxf(n0, 1e-15f);
  float e1 = tanhf(u0) / u0;
  float c1 = fmaxf(e1 * n0, 1e-15f);
  float v = acc * e1;
  if (c1 > MAXN) { v *= MAXN / c1; c1 = MAXN; }
  v *= artanh_f(c1) / c1; // logmap0
  v = fmaxf(v, 0.f);      // relu in tangent space
  float n2 = sqrtf(wredsum(v * v));
  float u2 = fmaxf(n2, 1e-15f);
  float e2 = tanhf(u2) / u2;
  float c2 = fmaxf(e2 * n2, 1e-15f);
  v *= e2;
  if (c2 > MAXN) { v *= MAXN / c2; c2 = MAXN; }
  v *= artanh_f(c2) / c2; // final logmap0
  return v;
}

// ---- stage A: HypLinear + hyp bias + logmap0 for all NP rows of this graph.
// wT: LDS transposed weight [IND][64]; xg: global rows (IND=128) or xsrc: LDS
// xn rows (IND=64). Output u -> LDS. Waves independent; no barriers inside.
template <int NP, int IND>
__device__ __forceinline__ void doA(int w, int j, const float* __restrict__ b,
                                    const float* wT, const float* xsrc,
                                    const float* __restrict__ xg, float* xrow,
                                    float* uOut) {
  // hb = proj(expmap0(b)) — per-layer constant, computed once per wave
  float bj = b[j];
  float nb = sqrtf(wredsum(bj * bj));
  float ub = fmaxf(nb, 1e-15f);
  float eb = tanhf(ub) / ub;
  float cb = fmaxf(eb * nb, 1e-15f);
  float hbj = bj * eb * ((cb > MAXN) ? MAXN / cb : 1.0f);
  float y2 = wredsum(hbj * hbj);

  constexpr int RPW = NP / 16;
  for (int rr = 0; rr < RPW; ++rr) {
    const int row = w * RPW + rr;
    const float* xr;
    if (IND == 128) {
      float* xw = xrow + w * 128;
      xw[j] = xg[(size_t)row * 128 + j];
      xw[64 + j] = xg[(size_t)row * 128 + 64 + j];
      xr = xw;
    } else {
      xr = xsrc + row * 64;
    }
    float x0 = xr[j];
    float a2 = x0 * x0;
    if (IND == 128) { float x1 = xr[64 + j]; a2 += x1 * x1; }
    float nx = sqrtf(wredsum(a2));
    float un = fmaxf(nx, 1e-15f);
    float s1 = tanhf(un) / un;
    float nv = s1 * nx;
    float nn = fmaxf(nv, 1e-15f);
    float s2 = (nn > MAXN) ? MAXN / nn : 1.0f;
    float alpha = s1 * s2;
    float xn = fmaxf(fminf(nn, MAXN), 1e-15f);

    float y = 0.f;
    for (int t = 0; t < IND; ++t) y = fmaf(xr[t], wT[t * 64 + j], y);
    float mxj = alpha * y;
    float mxn = fmaxf(sqrtf(wredsum(mxj * mxj)), 1e-15f);
    float hj = (tanhf(mxn / xn * artanh_f(xn)) / mxn) * mxj;

    float hn = fmaxf(sqrtf(wredsum(hj * hj)), 1e-15f);
    if (hn > MAXN) hj *= MAXN / hn;

    float x2 = wredsum(hj * hj);
    float xy = wredsum(hj * hbj);
    float num = (1.f + 2.f * xy + y2) * hj + (1.f - x2) * hbj;
    float den = fmaxf(1.f + 2.f * xy + x2 * y2, 1e-15f);
    float aj = num / den;

    float an = fmaxf(sqrtf(wredsum(aj * aj)), 1e-15f);
    float pn = an;
    if (an > MAXN) { aj *= MAXN / an; pn = MAXN; }
    uOut[row * 64 + j] = (artanh_f(pn) / pn) * aj;
  }
}

// ---- stage B: t = chain(adj @ u) (+ dis). u in LDS, adj global (L2-hot),
// register-tiled rows with uniform float4 broadcast adj loads.
template <int NP, bool WANTDIS>
__device__ __forceinline__ void doB(int w, int j, const float* __restrict__ adjg,
                                    const float* uIn, float* tOut, float* disL) {
  constexpr int RPW = NP / 16;
  constexpr int TR = RPW < 8 ? RPW : 8;
  for (int r0 = w * RPW; r0 < (w + 1) * RPW; r0 += TR) {
    float acc[TR], dsum[TR];
#pragma unroll
    for (int r = 0; r < TR; ++r) { acc[r] = 0.f; dsum[r] = 0.f; }
    for (int c0 = 0; c0 < NP; c0 += 4) {
      float uv0 = uIn[(c0 + 0) * 64 + j];
      float uv1 = uIn[(c0 + 1) * 64 + j];
      float uv2 = uIn[(c0 + 2) * 64 + j];
      float uv3 = uIn[(c0 + 3) * 64 + j];
#pragma unroll
      for (int r = 0; r < TR; ++r) {
        const float4 a4 = *(const float4*)(adjg + (size_t)(r0 + r) * NP + c0);
        acc[r] = fmaf(a4.x, uv0, acc[r]);
        acc[r] = fmaf(a4.y, uv1, acc[r]);
        acc[r] = fmaf(a4.z, uv2, acc[r]);
        acc[r] = fmaf(a4.w, uv3, acc[r]);
        if (WANTDIS) {
          dsum[r] += a4.x; dsum[r] += a4.y; dsum[r] += a4.z; dsum[r] += a4.w;
        }
      }
    }
#pragma unroll
    for (int r = 0; r < TR; ++r) {
      float v = chainB(acc[r]);
      tOut[(r0 + r) * 64 + j] = v;
      if (WANTDIS && j == 0)
        disL[r0 + r] = (dsum[r] > 0.f) ? (1.0f / sqrtf(dsum[r])) : 0.f;
    }
  }
}

// ---- stage C: score_i = sum_j | t_ij - dis_i * (adj @ (dis.*t))_ij |
template <int NP>
__device__ __forceinline__ void doC(int w, int j, const float* __restrict__ adjg,
                                    const float* tIn, const float* disL,
                                    float* scL) {
  constexpr int RPW = NP / 16;
  constexpr int TR = RPW < 8 ? RPW : 8;
  for (int r0 = w * RPW; r0 < (w + 1) * RPW; r0 += TR) {
    float acc[TR];
#pragma unroll
    for (int r = 0; r < TR; ++r) acc[r] = 0.f;
    for (int c0 = 0; c0 < NP; c0 += 4) {
      float uv0 = disL[c0 + 0] * tIn[(c0 + 0) * 64 + j];
      float uv1 = disL[c0 + 1] * tIn[(c0 + 1) * 64 + j];
      float uv2 = disL[c0 + 2] * tIn[(c0 + 2) * 64 + j];
      float uv3 = disL[c0 + 3] * tIn[(c0 + 3) * 64 + j];
#pragma unroll
      for (int r = 0; r < TR; ++r) {
        const float4 a4 = *(const float4*)(adjg + (size_t)(r0 + r) * NP + c0);
        acc[r] = fmaf(a4.x, uv0, acc[r]);
        acc[r] = fmaf(a4.y, uv1, acc[r]);
        acc[r] = fmaf(a4.z, uv2, acc[r]);
        acc[r] = fmaf(a4.w, uv3, acc[r]);
      }
    }
#pragma unroll
    for (int r = 0; r < TR; ++r) {
      float d = fabsf(tIn[(r0 + r) * 64 + j] - disL[r0 + r] * acc[r]);
      d = wredsum(d);
      if (j == 0) scL[r0 + r] = d;
    }
  }
}

// ---- stage D+E: exact top-k (jax tie-break) + xn + att proj + readout +
// structure-learned new adj. Contains 2 internal barriers (all threads reach).
template <int NP>
__device__ __forceinline__ void doDE(int tid, const float* __restrict__ att,
                                     const float* __restrict__ adjOld,
                                     float* __restrict__ adjNew, const float* tIn,
                                     const float* scL, float* svalL, int* selL,
                                     float* s1L, float* s2L, float* xnOut,
                                     float* x123L) {
  constexpr int K = NP / 2;
  if (tid < NP) {
    float si = scL[tid];
    int rank = 0;
    for (int c = 0; c < NP; ++c) {
      float v = scL[c];
      rank += (v > si) || (v == si && c < tid);
    }
    if (rank < K) { selL[rank] = tid; svalL[rank] = si; }
  }
  __syncthreads();
  if (tid < K) {
    int li = selL[tid];
    float tv = tanhf(svalL[tid]);
    float a = 0.f, b = 0.f;
    for (int jj = 0; jj < 64; ++jj) {
      float v = tIn[li * 64 + jj] * tv;
      xnOut[tid * 64 + jj] = v;
      a += v * att[jj];
      b += v * att[64 + jj];
    }
    s1L[tid] = a;
    s2L[tid] = b;
  }
  __syncthreads();
  if (tid < 64) {
    float mx = -1e30f, sm = 0.f;
    for (int r = 0; r < K; ++r) {
      float v = xnOut[r * 64 + tid];
      mx = fmaxf(mx, v);
      sm += v;
    }
    x123L[tid] = mx;
    x123L[64 + tid] = sm * (1.0f / K);
  }
  for (int idx = tid; idx < K * K; idx += 1024) {
    int ii = idx / K, jj = idx - ii * K;
    float e = s1L[ii] + s2L[jj];
    adjNew[idx] = fmaxf(e, 0.f) + adjOld[(size_t)selL[ii] * NP + selL[jj]];
  }
}

// ===== one block per graph; the entire forward pass in a single kernel =====
__global__ void __launch_bounds__(1024) k_mega(
    const float* __restrict__ x, const int* __restrict__ ei, int nE,
    const float* __restrict__ W1, const float* __restrict__ b1,
    const float* __restrict__ W2, const float* __restrict__ b2,
    const float* __restrict__ W3, const float* __restrict__ b3,
    const float* __restrict__ att1, const float* __restrict__ att2,
    const float* __restrict__ lw1, const float* __restrict__ lb1,
    const float* __restrict__ lw2, const float* __restrict__ lb2,
    const float* __restrict__ lw3, const float* __restrict__ lb3,
    float* __restrict__ adj1, float* __restrict__ adj2,
    float* __restrict__ adj3, float* __restrict__ out) {
  __shared__ float uLds[16384];   // 64KB: u rows / xn rows (re-used per layer)
  __shared__ float tLds[16384];   // 64KB: WT staging, then t rows
  __shared__ float xrow[16 * 128];
  __shared__ float srowL[256];
  __shared__ float disL[256];
  __shared__ float scL[256];
  __shared__ float svalL[128];
  __shared__ int selL[128];
  __shared__ float s1L[128];
  __shared__ float s2L[128];
  __shared__ float x123[384];
  __shared__ float h1[64];
  __shared__ float h2[32];
  __shared__ float zz[6];

  const int g = blockIdx.x;
  const int tid = threadIdx.x;
  const int w = tid >> 6, j = tid & 63;

  float* adj1g = adj1 + (size_t)g * 65536;
  float* adj2g = adj2 + (size_t)g * 16384;
  float* adj3g = adj3 + (size_t)g * 4096;
  const float* xg = x + (size_t)g * 256 * 128;

  // phase 0: zero adj1 slice; rowsum(x) -> srowL; stage W1T -> tLds
  for (int idx = tid * 4; idx < 65536; idx += 4096)
    *(float4*)(adj1g + idx) = make_float4(0.f, 0.f, 0.f, 0.f);
  for (int rr = 0; rr < 16; ++rr) {
    int row = w * 16 + rr;
    float a = xg[(size_t)row * 128 + j] + xg[(size_t)row * 128 + 64 + j];
    a = wredsum(a);
    if (j == 0) srowL[row] = a;
  }
  for (int idx = tid; idx < 64 * 128; idx += 1024)
    tLds[(idx & 127) * 64 + (idx >> 7)] = W1[idx];
  __syncthreads();

  // phase 1: edge scatter (this graph's contiguous edge slice) + stage A1
  {
    const int epg = nE >> 5; // edges per graph (4096)
    const int* er = ei;
    const int* ec = ei + nE;
    for (int e = g * epg + tid; e < (g + 1) * epg; e += 1024) {
      int r = er[e] & 255, c = ec[e] & 255;
      adj1g[r * 256 + c] = 0.5f * (srowL[r] + srowL[c]);
    }
  }
  doA<256, 128>(w, j, b1, tLds, nullptr, xg, xrow, uLds);
  __syncthreads();

  doB<256, true>(w, j, adj1g, uLds, tLds, disL); // t1 -> tLds (W1T dead)
  __syncthreads();
  doC<256>(w, j, adj1g, tLds, disL, scL);
  __syncthreads();
  // DE1: xn1 -> uLds[0:8192), adj2 (global), readout -> x123[0:128)
  doDE<256>(tid, att1, adj1g, adj2g, tLds, scL, svalL, selL, s1L, s2L, uLds,
            x123);
  __syncthreads();

  // ---- layer 2 ----
  for (int idx = tid; idx < 64 * 64; idx += 1024)
    tLds[(idx & 63) * 64 + (idx >> 6)] = W2[idx];
  __syncthreads();
  doA<128, 64>(w, j, b2, tLds, uLds /*xn1*/, nullptr, xrow, uLds + 8192);
  __syncthreads();
  doB<128, true>(w, j, adj2g, uLds + 8192, tLds, disL);
  __syncthreads();
  doC<128>(w, j, adj2g, tLds, disL, scL);
  __syncthreads();
  // DE2: xn2 -> uLds[0:4096) (xn1 dead), adj3, readout -> x123[128:256)
  doDE<128>(tid, att2, adj2g, adj3g, tLds, scL, svalL, selL, s1L, s2L, uLds,
            x123 + 128);
  __syncthreads();

  // ---- layer 3 ----
  for (int idx = tid; idx < 64 * 64; idx += 1024)
    tLds[(idx & 63) * 64 + (idx >> 6)] = W3[idx];
  __syncthreads();
  doA<64, 64>(w, j, b3, tLds, uLds /*xn2*/, nullptr, xrow, uLds + 4096);
  __syncthreads();
  doB<64, false>(w, j, adj3g, uLds + 4096, tLds, disL);
  __syncthreads();
  if (tid < 64) { // readout of t3 (64 rows)
    float mx = -1e30f, sm = 0.f;
    for (int r = 0; r < 64; ++r) {
      float v = tLds[r * 64 + tid];
      mx = fmaxf(mx, v);
      sm += v;
    }
    x123[256 + tid] = mx;
    x123[256 + 64 + tid] = sm * (1.0f / 64.0f);
  }
  __syncthreads();

  // ---- MLP head + log_softmax (reuse scL as r[128]) ----
  if (tid < 128)
    scL[tid] = fmaxf(x123[tid], 0.f) + fmaxf(x123[128 + tid], 0.f) +
               fmaxf(x123[256 + tid], 0.f);
  __syncthreads();
  if (tid < 64) {
    float acc = lb1[tid];
    for (int t = 0; t < 128; ++t) acc += scL[t] * lw1[(size_t)tid * 128 + t];
    h1[tid] = fmaxf(acc, 0.f);
  }
  __syncthreads();
  if (tid < 32) {
    float a = lb2[tid];
    for (int t = 0; t < 64; ++t) a += h1[t] * lw2[(size_t)tid * 64 + t];
    h2[tid] = fmaxf(a, 0.f);
  }
  __syncthreads();
  if (tid < 6) {
    float a = lb3[tid];
    for (int t = 0; t < 32; ++t) a += h2[t] * lw3[(size_t)tid * 32 + t];
    zz[tid] = a;
  }
  __syncthreads();
  if (tid < 6) {
    float m = zz[0];
    for (int c = 1; c < 6; ++c) m = fmaxf(m, zz[c]);
    float se = 0.f;
    for (int c = 0; c < 6; ++c) se += expf(zz[c] - m);
    out[(size_t)g * 6 + tid] = zz[tid] - m - logf(se);
  }
}

extern "C" void kernel_launch(void* const* d_in, const int* in_sizes, int n_in,
                              void* d_out, int out_size, void* d_ws,
                              size_t ws_size, hipStream_t stream) {
  const float* x = (const float*)d_in[0];
  const int* ei = (const int*)d_in[1];
  const float* W1 = (const float*)d_in[2];
  const float* b1 = (const float*)d_in[3];
  const float* W2 = (const float*)d_in[4];
  const float* b2 = (const float*)d_in[5];
  const float* W3 = (const float*)d_in[6];
  const float* b3 = (const float*)d_in[7];
  const float* att1 = (const float*)d_in[8];
  const float* att2 = (const float*)d_in[9];
  const float* lw1 = (const float*)d_in[10];
  const float* lb1 = (const float*)d_in[11];
  const float* lw2 = (const float*)d_in[12];
  const float* lb2 = (const float*)d_in[13];
  const float* lw3 = (const float*)d_in[14];
  const float* lb3 = (const float*)d_in[15];
  float* out = (float*)d_out;
  const int nE = in_sizes[1] / 2;

  float* p = (float*)d_ws;
  float* adj1 = p; p += (size_t)32 * 256 * 256;
  float* adj2 = p; p += (size_t)32 * 128 * 128;
  float* adj3 = p; p += (size_t)32 * 64 * 64;

  k_mega<<<32, 1024, 0, stream>>>(x, ei, nE, W1, b1, W2, b2, W3, b3, att1,
                                  att2, lw1, lb1, lw2, lb2, lw3, lb3, adj1,
                                  adj2, adj3, out);
}

// Round 3
// 329.922 us; speedup vs baseline: 2.2104x; 2.2104x over previous
//
#include <hip/hip_runtime.h>
#include <math.h>

#define MAXN 0.996f /* (1-PROJ_EPS)/sqrt(c) */

__device__ __forceinline__ float wredsum(float v) {
#pragma unroll
  for (int o = 32; o > 0; o >>= 1) v += __shfl_xor(v, o);
  return v;
}

__device__ __forceinline__ float artanh_f(float x) {
  x = fminf(fmaxf(x, -1.0f + 1e-7f), 1.0f - 1e-7f);
  return 0.5f * (log1pf(x) - log1pf(-x));
}

// HypAgg+HypAct+logmap0 nonlinear chain applied to one aggregated row value
__device__ __forceinline__ float chainB(float acc) {
  float n0 = sqrtf(wredsum(acc * acc));
  float u0 = fmaxf(n0, 1e-15f);
  float e1 = tanhf(u0) / u0;
  float c1 = fmaxf(e1 * n0, 1e-15f);
  float v = acc * e1;
  if (c1 > MAXN) { v *= MAXN / c1; c1 = MAXN; }
  v *= artanh_f(c1) / c1; // logmap0
  v = fmaxf(v, 0.f);      // relu in tangent space
  float n2 = sqrtf(wredsum(v * v));
  float u2 = fmaxf(n2, 1e-15f);
  float e2 = tanhf(u2) / u2;
  float c2 = fmaxf(e2 * n2, 1e-15f);
  v *= e2;
  if (c2 > MAXN) { v *= MAXN / c2; c2 = MAXN; }
  v *= artanh_f(c2) / c2; // final logmap0
  return v;
}

// per-row sum of x[N,128] -> s[N]; extra 3 blocks transpose W1,W2,W3
__global__ void k_rowsumT(const float* __restrict__ x, float* __restrict__ s,
                          const float* __restrict__ W1, const float* __restrict__ W2,
                          const float* __restrict__ W3, float* __restrict__ WT1,
                          float* __restrict__ WT2, float* __restrict__ WT3) {
  const int row = blockIdx.x, j = threadIdx.x;  // 64 threads
  if (row < 8192) {
    float a = x[(size_t)row * 128 + j] + x[(size_t)row * 128 + 64 + j];
    a = wredsum(a);
    if (j == 0) s[row] = a;
    return;
  }
  if (row == 8192) {
    for (int idx = j; idx < 64 * 128; idx += 64) WT1[(idx & 127) * 64 + (idx >> 7)] = W1[idx];
  } else if (row == 8193) {
    for (int idx = j; idx < 64 * 64; idx += 64) WT2[(idx & 63) * 64 + (idx >> 6)] = W2[idx];
  } else {
    for (int idx = j; idx < 64 * 64; idx += 64) WT3[(idx & 63) * 64 + (idx >> 6)] = W3[idx];
  }
}

// scatter edge weights into block-diagonal adj1 [32][256][256]
// (duplicate edges write identical values -> race is harmless)
__global__ void k_edges(const int* __restrict__ er, const int* __restrict__ ec,
                        const float* __restrict__ s, float* __restrict__ adj, int nE) {
  int e = blockIdx.x * blockDim.x + threadIdx.x;
  if (e >= nE) return;
  int r = er[e], c = ec[e];
  int g = r >> 8;
  adj[(((size_t)g * 256) + (r & 255)) * 256 + (c & 255)] = 0.5f * (s[r] + s[c]);
}

// HypLinear + hyperbolic bias + logmap0; one 64-lane wave per row.
// WT is the TRANSPOSED weight [IND][64] so loads are coalesced across lanes.
template <int IND>
__global__ void k_stageA(const float* __restrict__ x, const float* __restrict__ WT,
                         const float* __restrict__ b, float* __restrict__ u) {
  const int row = blockIdx.x;
  const int j = threadIdx.x;  // 64
  __shared__ float xs[IND];
  for (int t = j; t < IND; t += 64) xs[t] = x[(size_t)row * IND + t];
  __syncthreads();

  // hb = proj(expmap0(b))
  float bj = b[j];
  float nb = sqrtf(wredsum(bj * bj));
  float ub = fmaxf(nb, 1e-15f);
  float eb = tanhf(ub) / ub;
  float cb = fmaxf(eb * nb, 1e-15f);
  float hbj = bj * eb * ((cb > MAXN) ? MAXN / cb : 1.0f);
  float y2 = wredsum(hbj * hbj);

  // xh = proj(expmap0(x_row)) = alpha * x_row
  float a2 = 0.f;
  for (int t = j; t < IND; t += 64) a2 += xs[t] * xs[t];
  float nx = sqrtf(wredsum(a2));
  float un = fmaxf(nx, 1e-15f);
  float s1 = tanhf(un) / un;
  float nv = s1 * nx;
  float nn = fmaxf(nv, 1e-15f);
  float s2 = (nn > MAXN) ? MAXN / nn : 1.0f;
  float alpha = s1 * s2;
  float xn = fmaxf(fminf(nn, MAXN), 1e-15f);

  // mx = xh @ W.T  (coalesced: lane j reads WT[t][j])
  float y = 0.f;
  for (int t = 0; t < IND; ++t) y = fmaf(xs[t], WT[t * 64 + j], y);
  float mxj = alpha * y;
  float mxn = fmaxf(sqrtf(wredsum(mxj * mxj)), 1e-15f);
  float hj = (tanhf(mxn / xn * artanh_f(xn)) / mxn) * mxj;

  // proj
  float hn = fmaxf(sqrtf(wredsum(hj * hj)), 1e-15f);
  if (hn > MAXN) hj *= MAXN / hn;

  // mobius_add(h, hb)
  float x2 = wredsum(hj * hj);
  float xy = wredsum(hj * hbj);
  float num = (1.f + 2.f * xy + y2) * hj + (1.f - x2) * hbj;
  float den = fmaxf(1.f + 2.f * xy + x2 * y2, 1e-15f);
  float aj = num / den;

  // proj + logmap0
  float an = fmaxf(sqrtf(wredsum(aj * aj)), 1e-15f);
  float pn = an;
  if (an > MAXN) { aj *= MAXN / an; pn = MAXN; }
  u[(size_t)row * 64 + j] = (artanh_f(pn) / pn) * aj;
}

// stage B: t = chain(adj @ u) (+ dis). One wave per block, TR rows/wave
// register-tiled (u row traffic cut TR-x, adj loads float4). Grid = N/TR
// 64-thread blocks -> ~16 blocks/CU resident: latency fully hidden by TLP.
template <int NP, int TR, bool WANTDIS>
__global__ void __launch_bounds__(64) k_stageB(const float* __restrict__ adj,
                                               const float* __restrict__ u,
                                               float* __restrict__ t,
                                               float* __restrict__ dis) {
  const int row0 = blockIdx.x * TR;
  const int g = row0 / NP;
  const int r0 = row0 - g * NP;
  const int j = threadIdx.x;  // 64
  const float* adjg = adj + (size_t)g * NP * NP;
  const float* ug = u + (size_t)g * NP * 64;
  float acc[TR], dsum[TR];
#pragma unroll
  for (int r = 0; r < TR; ++r) { acc[r] = 0.f; dsum[r] = 0.f; }
  for (int c0 = 0; c0 < NP; c0 += 4) {
    float uv0 = ug[(c0 + 0) * 64 + j];
    float uv1 = ug[(c0 + 1) * 64 + j];
    float uv2 = ug[(c0 + 2) * 64 + j];
    float uv3 = ug[(c0 + 3) * 64 + j];
#pragma unroll
    for (int r = 0; r < TR; ++r) {
      const float4 a4 = *(const float4*)(adjg + (size_t)(r0 + r) * NP + c0);
      acc[r] = fmaf(a4.x, uv0, acc[r]);
      acc[r] = fmaf(a4.y, uv1, acc[r]);
      acc[r] = fmaf(a4.z, uv2, acc[r]);
      acc[r] = fmaf(a4.w, uv3, acc[r]);
      if (WANTDIS) {
        dsum[r] += a4.x; dsum[r] += a4.y; dsum[r] += a4.z; dsum[r] += a4.w;
      }
    }
  }
#pragma unroll
  for (int r = 0; r < TR; ++r) {
    float v = chainB(acc[r]);
    t[(size_t)(row0 + r) * 64 + j] = v;
    if (WANTDIS && j == 0)
      dis[row0 + r] = (dsum[r] > 0.f) ? (1.0f / sqrtf(dsum[r])) : 0.f;
  }
}

// stage C: score_i = sum_j | t_ij - dis_i * (adj @ (dis.*t))_ij |
template <int NP, int TR>
__global__ void __launch_bounds__(64) k_stageC(const float* __restrict__ adj,
                                               const float* __restrict__ t,
                                               const float* __restrict__ dis,
                                               float* __restrict__ score) {
  const int row0 = blockIdx.x * TR;
  const int g = row0 / NP;
  const int r0 = row0 - g * NP;
  const int j = threadIdx.x;  // 64
  const float* adjg = adj + (size_t)g * NP * NP;
  const float* tg = t + (size_t)g * NP * 64;
  const float* dg = dis + (size_t)g * NP;
  float acc[TR];
#pragma unroll
  for (int r = 0; r < TR; ++r) acc[r] = 0.f;
  for (int c0 = 0; c0 < NP; c0 += 4) {
    float uv0 = dg[c0 + 0] * tg[(c0 + 0) * 64 + j];
    float uv1 = dg[c0 + 1] * tg[(c0 + 1) * 64 + j];
    float uv2 = dg[c0 + 2] * tg[(c0 + 2) * 64 + j];
    float uv3 = dg[c0 + 3] * tg[(c0 + 3) * 64 + j];
#pragma unroll
    for (int r = 0; r < TR; ++r) {
      const float4 a4 = *(const float4*)(adjg + (size_t)(r0 + r) * NP + c0);
      acc[r] = fmaf(a4.x, uv0, acc[r]);
      acc[r] = fmaf(a4.y, uv1, acc[r]);
      acc[r] = fmaf(a4.z, uv2, acc[r]);
      acc[r] = fmaf(a4.w, uv3, acc[r]);
    }
  }
#pragma unroll
  for (int r = 0; r < TR; ++r) {
    float d = fabsf(tg[(size_t)(r0 + r) * 64 + j] - dg[r0 + r] * acc[r]);
    d = wredsum(d);
    if (j == 0) score[row0 + r] = d;
  }
}

// fused top-k select + xn + attention projections + readout + structure-learn adj
template <int NPGL>
__global__ void k_stageDE(const float* __restrict__ score, const float* __restrict__ t,
                          const float* __restrict__ att, const float* __restrict__ adj_old,
                          float* __restrict__ xn, float* __restrict__ adj_new,
                          float* __restrict__ xread) {
  constexpr int K = NPGL / 2;
  const int g = blockIdx.x;
  const int i = threadIdx.x;  // NPGL threads
  __shared__ float sc[NPGL];
  __shared__ int sel[K];
  __shared__ float sval[K];
  __shared__ float xs[K * 64];
  __shared__ float s1s[K];
  __shared__ float s2s[K];
  sc[i] = score[(size_t)g * NPGL + i];
  __syncthreads();
  float si = sc[i];
  int rank = 0;
  for (int c = 0; c < NPGL; ++c) { float v = sc[c]; rank += (v > si) || (v == si && c < i); }
  if (rank < K) { sel[rank] = i; sval[rank] = si; }
  __syncthreads();
  if (i < K) {
    int li = sel[i];
    float tv = tanhf(sval[i]);
    const float* trow = t + ((size_t)g * NPGL + li) * 64;
    float* xout = xn + ((size_t)g * K + i) * 64;
    float a = 0.f, b = 0.f;
    for (int jj = 0; jj < 64; ++jj) {
      float v = trow[jj] * tv;
      xs[i * 64 + jj] = v;
      a += v * att[jj];
      b += v * att[64 + jj];
      xout[jj] = v;
    }
    s1s[i] = a;
    s2s[i] = b;
  }
  __syncthreads();
  if (i < 64) {
    float mx = -1e30f, sm = 0.f;
    for (int r = 0; r < K; ++r) { float v = xs[r * 64 + i]; mx = fmaxf(mx, v); sm += v; }
    xread[(size_t)g * 128 + i] = mx;
    xread[(size_t)g * 128 + 64 + i] = sm * (1.0f / K);
  }
  const float* aog = adj_old + (size_t)g * NPGL * NPGL;
  float* ang = adj_new + (size_t)g * K * K;
  for (int idx = i; idx < K * K; idx += NPGL) {
    int ii = idx / K, jj = idx - ii * K;
    float e = s1s[ii] + s2s[jj];
    ang[idx] = fmaxf(e, 0.f) + aog[(size_t)sel[ii] * NPGL + sel[jj]];
  }
}

// fused layer 3 + MLP head: one block per graph, 512 threads = 8 waves x 8 rows.
// A3 (HypLinear chain) -> B3 (HypAgg chain) -> readout -> MLP -> log_softmax.
__global__ void __launch_bounds__(512) k_tail(
    const float* __restrict__ xn2, const float* __restrict__ W3,
    const float* __restrict__ b3, const float* __restrict__ adj3,
    const float* __restrict__ x1, const float* __restrict__ x2,
    const float* __restrict__ lw1, const float* __restrict__ lb1,
    const float* __restrict__ lw2, const float* __restrict__ lb2,
    const float* __restrict__ lw3, const float* __restrict__ lb3,
    float* __restrict__ out) {
  const int g = blockIdx.x;
  const int tid = threadIdx.x;  // 512
  const int w = tid >> 6, j = tid & 63;
  __shared__ float xs[4096];   // xn2 rows of this graph
  __shared__ float wT[4096];   // W3 transposed
  __shared__ float uL[4096];   // u3
  __shared__ float tL[4096];   // t3
  __shared__ float rr_[128];
  __shared__ float h1[64];
  __shared__ float h2[32];
  __shared__ float zz[6];

  const float* xg = xn2 + (size_t)g * 4096;
  for (int idx = tid * 4; idx < 4096; idx += 2048)
    *(float4*)(xs + idx) = *(const float4*)(xg + idx);
  for (int idx = tid; idx < 4096; idx += 512)
    wT[(idx & 63) * 64 + (idx >> 6)] = W3[idx];
  __syncthreads();

  // ---- A3: 8 rows per wave ----
  float bj = b3[j];
  float nb = sqrtf(wredsum(bj * bj));
  float ub = fmaxf(nb, 1e-15f);
  float eb = tanhf(ub) / ub;
  float cb = fmaxf(eb * nb, 1e-15f);
  float hbj = bj * eb * ((cb > MAXN) ? MAXN / cb : 1.0f);
  float y2 = wredsum(hbj * hbj);
  for (int rr = 0; rr < 8; ++rr) {
    const int row = w * 8 + rr;
    const float* xr = xs + row * 64;
    float x0 = xr[j];
    float nx = sqrtf(wredsum(x0 * x0));
    float un = fmaxf(nx, 1e-15f);
    float s1 = tanhf(un) / un;
    float nv = s1 * nx;
    float nn = fmaxf(nv, 1e-15f);
    float s2 = (nn > MAXN) ? MAXN / nn : 1.0f;
    float alpha = s1 * s2;
    float xnn = fmaxf(fminf(nn, MAXN), 1e-15f);
    float y = 0.f;
    for (int t = 0; t < 64; ++t) y = fmaf(xr[t], wT[t * 64 + j], y);
    float mxj = alpha * y;
    float mxn = fmaxf(sqrtf(wredsum(mxj * mxj)), 1e-15f);
    float hj = (tanhf(mxn / xnn * artanh_f(xnn)) / mxn) * mxj;
    float hn = fmaxf(sqrtf(wredsum(hj * hj)), 1e-15f);
    if (hn > MAXN) hj *= MAXN / hn;
    float x2v = wredsum(hj * hj);
    float xy = wredsum(hj * hbj);
    float num = (1.f + 2.f * xy + y2) * hj + (1.f - x2v) * hbj;
    float den = fmaxf(1.f + 2.f * xy + x2v * y2, 1e-15f);
    float aj = num / den;
    float an = fmaxf(sqrtf(wredsum(aj * aj)), 1e-15f);
    float pn = an;
    if (an > MAXN) { aj *= MAXN / an; pn = MAXN; }
    uL[row * 64 + j] = (artanh_f(pn) / pn) * aj;
  }
  __syncthreads();

  // ---- B3: 8 rows per wave, register-tiled ----
  const float* adjg = adj3 + (size_t)g * 4096;
  {
    float acc[8];
#pragma unroll
    for (int r = 0; r < 8; ++r) acc[r] = 0.f;
    for (int c0 = 0; c0 < 64; c0 += 4) {
      float uv0 = uL[(c0 + 0) * 64 + j];
      float uv1 = uL[(c0 + 1) * 64 + j];
      float uv2 = uL[(c0 + 2) * 64 + j];
      float uv3 = uL[(c0 + 3) * 64 + j];
#pragma unroll
      for (int r = 0; r < 8; ++r) {
        const float4 a4 = *(const float4*)(adjg + (size_t)(w * 8 + r) * 64 + c0);
        acc[r] = fmaf(a4.x, uv0, acc[r]);
        acc[r] = fmaf(a4.y, uv1, acc[r]);
        acc[r] = fmaf(a4.z, uv2, acc[r]);
        acc[r] = fmaf(a4.w, uv3, acc[r]);
      }
    }
#pragma unroll
    for (int r = 0; r < 8; ++r) tL[(w * 8 + r) * 64 + j] = chainB(acc[r]);
  }
  __syncthreads();

  // ---- readout t3 + combine with x1,x2 ----
  if (tid < 64) {
    float mx = -1e30f, sm = 0.f;
    for (int r = 0; r < 64; ++r) {
      float v = tL[r * 64 + tid];
      mx = fmaxf(mx, v);
      sm += v;
    }
    rr_[tid] = fmaxf(x1[(size_t)g * 128 + tid], 0.f) +
               fmaxf(x2[(size_t)g * 128 + tid], 0.f) + fmaxf(mx, 0.f);
    rr_[64 + tid] = fmaxf(x1[(size_t)g * 128 + 64 + tid], 0.f) +
                    fmaxf(x2[(size_t)g * 128 + 64 + tid], 0.f) +
                    fmaxf(sm * (1.0f / 64.0f), 0.f);
  }
  __syncthreads();
  if (tid < 64) {
    float acc = lb1[tid];
    for (int t = 0; t < 128; ++t) acc += rr_[t] * lw1[(size_t)tid * 128 + t];
    h1[tid] = fmaxf(acc, 0.f);
  }
  __syncthreads();
  if (tid < 32) {
    float a = lb2[tid];
    for (int t = 0; t < 64; ++t) a += h1[t] * lw2[(size_t)tid * 64 + t];
    h2[tid] = fmaxf(a, 0.f);
  }
  __syncthreads();
  if (tid < 6) {
    float a = lb3[tid];
    for (int t = 0; t < 32; ++t) a += h2[t] * lw3[(size_t)tid * 32 + t];
    zz[tid] = a;
  }
  __syncthreads();
  if (tid < 6) {
    float m = zz[0];
    for (int c = 1; c < 6; ++c) m = fmaxf(m, zz[c]);
    float se = 0.f;
    for (int c = 0; c < 6; ++c) se += expf(zz[c] - m);
    out[(size_t)g * 6 + tid] = zz[tid] - m - logf(se);
  }
}

extern "C" void kernel_launch(void* const* d_in, const int* in_sizes, int n_in,
                              void* d_out, int out_size, void* d_ws,
                              size_t ws_size, hipStream_t stream) {
  const float* x = (const float*)d_in[0];
  const int* ei = (const int*)d_in[1];
  const float* W1 = (const float*)d_in[2];
  const float* b1 = (const float*)d_in[3];
  const float* W2 = (const float*)d_in[4];
  const float* b2 = (const float*)d_in[5];
  const float* W3 = (const float*)d_in[6];
  const float* b3 = (const float*)d_in[7];
  const float* att1 = (const float*)d_in[8];
  const float* att2 = (const float*)d_in[9];
  const float* lw1 = (const float*)d_in[10];
  const float* lb1 = (const float*)d_in[11];
  const float* lw2 = (const float*)d_in[12];
  const float* lb2 = (const float*)d_in[13];
  const float* lw3 = (const float*)d_in[14];
  const float* lb3 = (const float*)d_in[15];
  float* out = (float*)d_out;
  const int nE = in_sizes[1] / 2;

  float* p = (float*)d_ws;
  float* srow = p;  p += 8192;
  float* adj1 = p;  p += (size_t)32 * 256 * 256;
  float* adj2 = p;  p += (size_t)32 * 128 * 128;
  float* adj3 = p;  p += (size_t)32 * 64 * 64;
  float* ubuf = p;  p += (size_t)8192 * 64;
  float* t1 = p;    p += (size_t)8192 * 64;
  float* t2 = p;    p += (size_t)4096 * 64;
  float* dis = p;   p += 8192;
  float* score = p; p += 8192;
  float* xn1 = p;   p += (size_t)4096 * 64;
  float* xn2 = p;   p += (size_t)2048 * 64;
  float* x1 = p;    p += 32 * 128;
  float* x2 = p;    p += 32 * 128;
  float* WT1 = p;   p += 128 * 64;
  float* WT2 = p;   p += 64 * 64;
  float* WT3 = p;   p += 64 * 64;

  hipMemsetAsync(adj1, 0, (size_t)32 * 256 * 256 * sizeof(float), stream);
  k_rowsumT<<<8195, 64, 0, stream>>>(x, srow, W1, W2, W3, WT1, WT2, WT3);
  k_edges<<<(nE + 255) / 256, 256, 0, stream>>>(ei, ei + nE, srow, adj1, nE);

  // layer 1 (N=8192, graph=256)
  k_stageA<128><<<8192, 64, 0, stream>>>(x, WT1, b1, ubuf);
  k_stageB<256, 4, true><<<2048, 64, 0, stream>>>(adj1, ubuf, t1, dis);
  k_stageC<256, 4><<<2048, 64, 0, stream>>>(adj1, t1, dis, score);
  k_stageDE<256><<<32, 256, 0, stream>>>(score, t1, att1, adj1, xn1, adj2, x1);

  // layer 2 (N=4096, graph=128)
  k_stageA<64><<<4096, 64, 0, stream>>>(xn1, WT2, b2, ubuf);
  k_stageB<128, 4, true><<<1024, 64, 0, stream>>>(adj2, ubuf, t2, dis);
  k_stageC<128, 4><<<1024, 64, 0, stream>>>(adj2, t2, dis, score);
  k_stageDE<128><<<32, 128, 0, stream>>>(score, t2, att2, adj2, xn2, adj3, x2);

  // layer 3 + MLP head fused (32 graphs)
  k_tail<<<32, 512, 0, stream>>>(xn2, W3, b3, adj3, x1, x2, lw1, lb1, lw2,
                                 lb2, lw3, lb3, out);
}